// Round 3
// baseline (1822.941 us; speedup 1.0000x reference)
//
#include <hip/hip_runtime.h>
#include <hip/hip_bf16.h>

// CTRNN forward, B=256 T=2048 D=32 H=64. ALL tensors fp32 (per reference).
// Dtype forensics: r1 (bf16 reads of fp32 data) -> inf via low-half mantissa
// bits misread as exponents; r2 (fp32 reads, bf16 STORES) -> err exactly
// max|ref|=4.03125 because bf16 stores into the fp32-checked out buffer leave
// the ref-max fp32 slot ~0. => inputs fp32, OUTPUT fp32.
// seq_lengths only gates gradients in the reference -> forward ignores it.
// One wave per batch (grid=256, block=64). Lane h owns hidden unit h and
// keeps W_hh[h][:] (64 regs) + W_in[h][:] (32 regs) in VGPRs. Hidden state
// broadcast through double-buffered LDS; x rows prefetched 2 steps ahead.

#define Bb 256
#define Tt 2048
#define Dd 32
#define Hh 64

static constexpr float ALPHA = (float)(16.67 / 40.0);
static constexpr float OMA   = 1.0f - ALPHA;

__global__ __launch_bounds__(64) void ctrnn_fwd(
    const float* __restrict__ x,
    const float* __restrict__ W_in,
    const float* __restrict__ b_in,
    const float* __restrict__ W_hh,
    const float* __restrict__ b_hh,
    float* __restrict__ out)
{
    const int b    = blockIdx.x;
    const int lane = threadIdx.x;

    __shared__ alignas(16) float hc[2][Hh];   // double-buffered hidden state
    __shared__ alignas(16) float xs[2][Dd];   // double-buffered x row

    // Per-lane weights in registers (fully unrolled indexing -> VGPRs).
    float whh[Hh];
#pragma unroll
    for (int k = 0; k < Hh; ++k) whh[k] = W_hh[lane * Hh + k];
    float win[Dd];
#pragma unroll
    for (int d = 0; d < Dd; ++d) win[d] = W_in[lane * Dd + d];
    const float cb = ALPHA * (b_in[lane] + b_hh[lane]);

    hc[0][lane] = 0.0f;

    const float* xrow = x + (size_t)b * Tt * Dd;
    float p0 = 0.0f, p1 = 0.0f;
    if (lane < Dd) {
        xs[0][lane] = xrow[lane];              // x[t=0]
        p0 = xrow[Dd + lane];                  // x[t=1]
        p1 = xrow[2 * Dd + lane];              // x[t=2]
    }
    __syncthreads();

    float* orow  = out + (size_t)b * Tt * Hh + lane;
    float* hlast = out + (size_t)Bb * Tt * Hh + (size_t)b * Hh + lane;

    int cur = 0;
    float hnew = 0.0f;
    for (int t = 0; t < Tt; ++t) {
        const int nxt = cur ^ 1;

        // Stage x[t+1] into the other buffer; keep prefetch 2 steps deep.
        if (lane < Dd) {
            xs[nxt][lane] = p0;
            p0 = p1;
            const int tf = (t + 3 < Tt) ? (t + 3) : (Tt - 1);
            p1 = xrow[(size_t)tf * Dd + lane];
        }

        // Recurrent matvec: lane h computes sum_k W_hh[h][k] * h[k].
        float a0 = 0.0f, a1 = 0.0f, a2 = 0.0f, a3 = 0.0f;
        const float4* h4 = reinterpret_cast<const float4*>(hc[cur]);
#pragma unroll
        for (int j = 0; j < Hh / 4; ++j) {
            const float4 hv = h4[j];   // broadcast ds_read_b128
            a0 = fmaf(whh[4 * j + 0], hv.x, a0);
            a1 = fmaf(whh[4 * j + 1], hv.y, a1);
            a2 = fmaf(whh[4 * j + 2], hv.z, a2);
            a3 = fmaf(whh[4 * j + 3], hv.w, a3);
        }
        // Fused input projection: sum_d W_in[h][d] * x[t][d].
        const float4* x4 = reinterpret_cast<const float4*>(xs[cur]);
#pragma unroll
        for (int j = 0; j < Dd / 4; ++j) {
            const float4 xv = x4[j];   // broadcast ds_read_b128
            a0 = fmaf(win[4 * j + 0], xv.x, a0);
            a1 = fmaf(win[4 * j + 1], xv.y, a1);
            a2 = fmaf(win[4 * j + 2], xv.z, a2);
            a3 = fmaf(win[4 * j + 3], xv.w, a3);
        }

        const float hold = hc[cur][lane];
        hnew = fmaxf(OMA * hold + ALPHA * ((a0 + a1) + (a2 + a3)) + cb, 0.0f);
        hc[nxt][lane] = hnew;
        orow[(size_t)t * Hh] = hnew;

        __syncthreads();   // h[nxt] visible + old buffers reusable next step
        cur = nxt;
    }
    *hlast = hnew;
}

extern "C" void kernel_launch(void* const* d_in, const int* in_sizes, int n_in,
                              void* d_out, int out_size, void* d_ws, size_t ws_size,
                              hipStream_t stream) {
    const float* x    = (const float*)d_in[0];
    // d_in[1] = seq_lengths (int32): forward value is mask-independent.
    const float* W_in = (const float*)d_in[2];
    const float* b_in = (const float*)d_in[3];
    const float* W_hh = (const float*)d_in[4];
    const float* b_hh = (const float*)d_in[5];
    float* out = (float*)d_out;

    ctrnn_fwd<<<dim3(Bb), dim3(64), 0, stream>>>(x, W_in, b_in, W_hh, b_hh, out);
}

// Round 4
// 917.138 us; speedup vs baseline: 1.9876x; 1.9876x over previous
//
#include <hip/hip_runtime.h>

// CTRNN forward, B=256 T=2048 D=32 H=64. ALL tensors fp32 (r3 passed, 0.0078).
// r3 post-mortem: 1985 cyc/step — __syncthreads forced vmcnt(0) drain of the
// per-step x prefetch load (~900cyc HBM) + h store every step. Fix: single
// wave per block (no barriers at all), and move the input projection to a
// separate parallel kernel that writes xp into `out` in-place; the recurrence
// reads xp rows 8 deep ahead (register ring) and overwrites them with h.

#define Bb 256
#define Tt 2048
#define Dd 32
#define Hh 64

typedef float v2f __attribute__((ext_vector_type(2)));

static constexpr float ALPHA = (float)(16.67 / 40.0);
static constexpr float OMA   = 1.0f - ALPHA;

static __device__ inline v2f vfma2(v2f a, v2f b, v2f c) {
#if __has_builtin(__builtin_elementwise_fma)
    return __builtin_elementwise_fma(a, b, c);
#else
    v2f r; r.x = fmaf(a.x, b.x, c.x); r.y = fmaf(a.y, b.y, c.y); return r;
#endif
}

// ---------------- Phase A: out[b][t][h] = dot(x[b][t][:], W_in[h][:]) -------
// grid 2048 = 256 b x 8 tiles, block 256 (4 waves). Wave w covers 64 steps.
// Lane h keeps its W_in row in regs; x[t] is a broadcast read (same addr all
// lanes, L1-served); stores coalesced (lane = fastest output dim).
__global__ __launch_bounds__(256) void ctrnn_xproj(
    const float* __restrict__ x,
    const float* __restrict__ W_in,
    float* __restrict__ out)
{
    const int lane = threadIdx.x & 63;
    const int wave = threadIdx.x >> 6;
    const int b    = blockIdx.x >> 3;
    const int tile = blockIdx.x & 7;
    const int t0   = tile * 256 + wave * 64;

    float4 w[8];
    const float4* wrow = reinterpret_cast<const float4*>(W_in + lane * Dd);
#pragma unroll
    for (int j = 0; j < 8; ++j) w[j] = wrow[j];

    const float* xb = x + (size_t)b * Tt * Dd;
    float*       ob = out + (size_t)b * Tt * Hh;

    for (int i = 0; i < 64; ++i) {
        const int t = t0 + i;
        const float4* xr = reinterpret_cast<const float4*>(xb + (size_t)t * Dd);
        float s0 = 0.f, s1 = 0.f, s2 = 0.f, s3 = 0.f;
#pragma unroll
        for (int j = 0; j < 8; ++j) {
            const float4 xv = xr[j];
            s0 = fmaf(w[j].x, xv.x, s0);
            s1 = fmaf(w[j].y, xv.y, s1);
            s2 = fmaf(w[j].z, xv.z, s2);
            s3 = fmaf(w[j].w, xv.w, s3);
        }
        ob[(size_t)t * Hh + lane] = (s0 + s1) + (s2 + s3);
    }
}

// ---------------- Phase B: sequential recurrence, 1 wave per batch ----------
// No __syncthreads anywhere: single wave, LDS deps ordered by lgkmcnt only.
// xp read from out rows (written by phase A), 8-deep register ring prefetch;
// row t is overwritten with h_t after its xp is consumed (same-lane ordering).
__global__ __launch_bounds__(64) void ctrnn_recur(
    const float* __restrict__ b_in,
    const float* __restrict__ W_hh,
    const float* __restrict__ b_hh,
    float* __restrict__ out)
{
    const int b    = blockIdx.x;
    const int lane = threadIdx.x;

    __shared__ alignas(16) float hs[Hh];

    v2f w[Hh / 2];
    const v2f* wrow = reinterpret_cast<const v2f*>(W_hh + lane * Hh);
#pragma unroll
    for (int j = 0; j < Hh / 2; ++j) w[j] = wrow[j];
    const float cb = ALPHA * (b_in[lane] + b_hh[lane]);

    hs[lane] = 0.0f;   // single wave: ordered vs later ds_reads by lgkmcnt

    float* ob = out + (size_t)b * Tt * Hh + lane;

    float xp[8];
#pragma unroll
    for (int j = 0; j < 8; ++j) xp[j] = ob[(size_t)j * Hh];

    float hold = 0.0f;
    for (int t = 0; t < Tt; t += 8) {
#pragma unroll
        for (int j = 0; j < 8; ++j) {
            // matvec: lane h computes sum_k W_hh[h][k] * hs[k] (broadcast reads)
            const float4* h4 = reinterpret_cast<const float4*>(hs);
            v2f acc0 = {0.f, 0.f}, acc1 = {0.f, 0.f};
#pragma unroll
            for (int k = 0; k < 16; ++k) {
                const float4 hv = h4[k];
                const v2f h01 = {hv.x, hv.y};
                const v2f h23 = {hv.z, hv.w};
                acc0 = vfma2(w[2 * k + 0], h01, acc0);
                acc1 = vfma2(w[2 * k + 1], h23, acc1);
            }
            const v2f accs = acc0 + acc1;
            const float sum = (accs.x + accs.y) + xp[j];
            const float hnew = fmaxf(fmaf(ALPHA, sum, fmaf(OMA, hold, cb)), 0.0f);

            ob[(size_t)(t + j) * Hh] = hnew;        // overwrite xp row with h
            hs[lane] = hnew;                        // next step's broadcast src
            hold = hnew;

            // refill ring 8 ahead (in-bounds even past Tt: lands in the
            // hlast region rows, value never consumed)
            xp[j] = ob[(size_t)(t + j + 8) * Hh];
        }
    }
    // h_last
    out[(size_t)Bb * Tt * Hh + (size_t)b * Hh + lane] = hold;
}

extern "C" void kernel_launch(void* const* d_in, const int* in_sizes, int n_in,
                              void* d_out, int out_size, void* d_ws, size_t ws_size,
                              hipStream_t stream) {
    const float* x    = (const float*)d_in[0];
    // d_in[1] = seq_lengths (int32): forward value is mask-independent.
    const float* W_in = (const float*)d_in[2];
    const float* b_in = (const float*)d_in[3];
    const float* W_hh = (const float*)d_in[4];
    const float* b_hh = (const float*)d_in[5];
    float* out = (float*)d_out;

    ctrnn_xproj<<<dim3(Bb * 8), dim3(256), 0, stream>>>(x, W_in, out);
    ctrnn_recur<<<dim3(Bb), dim3(64), 0, stream>>>(b_in, W_hh, b_hh, out);
}